// Round 12
// baseline (34.856 us; speedup 1.0000x reference)
//
#include <hip/hip_runtime.h>
#include <cstdint>

#define NN 1024      // nodes
#define NE 16384     // edges
#define DF 256       // features
#define UB 2.0f      // upper bound
#define MAXSEL 6
#define CAP 128      // slot capacity per node (max degree ~40 for this input)
#define NB2 1024     // k_dist_build blocks (16 edges per block)
#define DSTR 16      // deg stride: 1 word per 64B line

typedef unsigned long long u64;

// ---- K0: zero deg (padded) + maskT (192KB, contiguous) ----
__global__ void k_zero(uint4* __restrict__ p) {
    p[blockIdx.x * 256 + threadIdx.x] = make_uint4(0, 0, 0, 0);
}

// ---- K1: per-edge L2 distance + slotted lists + block min/max ----
// 16 lanes per edge (4 float4 loads each), 4 edges per wave, 16 per block.
// Butterfly reduce (xor 1,2,4,8) gives every lane its edge's full sum; two
// more butterflies (16,32) give the wave min/max of the 4 edges' dist bits.
// Slot key packs (distbits:32 | edge_id:14 | dst:10): u64 ordering == ordering
// by (dist, edge_id) == (score, edge_id) since score is monotone affine in dist.
__global__ void k_dist_build(const float* __restrict__ x, const int* __restrict__ src,
                             const int* __restrict__ dst, int* __restrict__ deg,
                             u64* __restrict__ slots,
                             uint32_t* __restrict__ pmin, uint32_t* __restrict__ pmax) {
    __shared__ uint32_t smin[4], smax[4];
    int t = threadIdx.x;
    int wid = t >> 6, lane = t & 63;
    int c16 = lane & 15;
    int e = blockIdx.x * 16 + wid * 4 + (lane >> 4);
    int u = src[e], v = dst[e];
    const float4* xa = (const float4*)(x + (size_t)u * DF);
    const float4* xb = (const float4*)(x + (size_t)v * DF);
    float4 a0 = xa[c16],      b0 = xb[c16];
    float4 a1 = xa[c16 + 16], b1 = xb[c16 + 16];
    float4 a2 = xa[c16 + 32], b2 = xb[c16 + 32];
    float4 a3 = xa[c16 + 48], b3 = xb[c16 + 48];
    double s = 0.0;
    {
        float d;
        d = a0.x-b0.x; s += (double)d*d;  d = a0.y-b0.y; s += (double)d*d;
        d = a0.z-b0.z; s += (double)d*d;  d = a0.w-b0.w; s += (double)d*d;
        d = a1.x-b1.x; s += (double)d*d;  d = a1.y-b1.y; s += (double)d*d;
        d = a1.z-b1.z; s += (double)d*d;  d = a1.w-b1.w; s += (double)d*d;
        d = a2.x-b2.x; s += (double)d*d;  d = a2.y-b2.y; s += (double)d*d;
        d = a2.z-b2.z; s += (double)d*d;  d = a2.w-b2.w; s += (double)d*d;
        d = a3.x-b3.x; s += (double)d*d;  d = a3.y-b3.y; s += (double)d*d;
        d = a3.z-b3.z; s += (double)d*d;  d = a3.w-b3.w; s += (double)d*d;
    }
    s += __shfl_xor(s, 1, 64);
    s += __shfl_xor(s, 2, 64);
    s += __shfl_xor(s, 4, 64);
    s += __shfl_xor(s, 8, 64);                    // all 16 lanes hold edge sum
    uint32_t db = __float_as_uint(sqrtf((float)s));
    if (c16 == 0) {                               // 4 lanes: one per edge
        int pos = atomicAdd(&deg[u * DSTR], 1);
        if (pos < CAP)
            slots[(size_t)u * CAP + pos] =
                ((u64)db << 24) | ((u64)(uint32_t)e << 10) | (u64)(uint32_t)v;
    }
    uint32_t mnv = db, mxv = db;
    uint32_t o;
    o = (uint32_t)__shfl_xor((int)mnv, 16, 64); mnv = min(mnv, o);
    o = (uint32_t)__shfl_xor((int)mnv, 32, 64); mnv = min(mnv, o);
    o = (uint32_t)__shfl_xor((int)mxv, 16, 64); mxv = max(mxv, o);
    o = (uint32_t)__shfl_xor((int)mxv, 32, 64); mxv = max(mxv, o);
    if (lane == 0) { smin[wid] = mnv; smax[wid] = mxv; }
    __syncthreads();
    if (t == 0) {
        pmin[blockIdx.x] = min(min(smin[0], smin[1]), min(smin[2], smin[3]));
        pmax[blockIdx.x] = max(max(smax[0], smax[1]), max(smax[2], smax[3]));
    }
}

// ---- K2: greedy cluster search, 1 wave per seed ----
// degL prefetch (parallel) + flattened member scan: all slot loads independent.
// Also writes sig, masks, unfiltered maskT scatter, and dc64 (packed dup
// candidates: members v<i, for k_rows' dedup — 1 load/j instead of ~7).
__global__ void k_search(const int* __restrict__ deg, const u64* __restrict__ slots,
                         const uint32_t* __restrict__ pmin, const uint32_t* __restrict__ pmax,
                         const int* __restrict__ src,
                         uint32_t* __restrict__ masks, uint32_t* __restrict__ maskT,
                         int* __restrict__ selU, int* __restrict__ selV,
                         float* __restrict__ selS, int* __restrict__ selCnt,
                         u64* __restrict__ sig, u64* __restrict__ dc64) {
    __shared__ uint32_t inc[32];
    __shared__ int members[8];
    __shared__ int degL[8], offL[9];
    __shared__ float s_tot;
    __shared__ int s_nmem;
    int i = blockIdx.x, lane = threadIdx.x;
    if (lane < 32) inc[lane] = 0;

    // reduce 1024 block partials -> MN, MX (uint4 loads, 4 iters/lane)
    uint32_t mnb = 0xFFFFFFFFu, mxb = 0u;
    const uint4* p4n = (const uint4*)pmin;
    const uint4* p4x = (const uint4*)pmax;
    for (int k = lane; k < NB2 / 4; k += 64) {
        uint4 a = p4n[k], b = p4x[k];
        mnb = min(mnb, min(min(a.x, a.y), min(a.z, a.w)));
        mxb = max(mxb, max(max(b.x, b.y), max(b.z, b.w)));
    }
    for (int off = 32; off; off >>= 1) {
        uint32_t oa = (uint32_t)__shfl_xor((int)mnb, off, 64);
        uint32_t ob = (uint32_t)__shfl_xor((int)mxb, off, 64);
        mnb = min(mnb, oa);
        mxb = max(mxb, ob);
    }
    float MN = __uint_as_float(mnb);
    float MX = __uint_as_float(mxb);

    if (lane == 0) {
        inc[i >> 5] = 1u << (i & 31);
        members[0] = i;
        s_tot = 0.0f;
        s_nmem = 1;
    }
    __syncthreads();
    int cnt = 0;
    for (int step = 0; step < MAXSEL; ++step) {
        if (s_tot >= UB) break;                      // uniform LDS scalar
        int nm = s_nmem;
        if (lane < nm) degL[lane] = min(deg[members[lane] * DSTR], CAP);
        __syncthreads();
        if (lane == 0) {
            offL[0] = 0;
            for (int m = 0; m < nm; ++m) offL[m + 1] = offL[m] + degL[m];
        }
        __syncthreads();
        int T = offL[nm];
        u64 best = ~0ull;
        for (int f = lane; f < T; f += 64) {
            int m = 0;
            while (f >= offL[m + 1]) ++m;            // <=7 LDS iters
            u64 en = slots[(size_t)members[m] * CAP + (f - offL[m])];
            int v = (int)(en & 1023);
            if (!((inc[v >> 5] >> (v & 31)) & 1u) && en < best) best = en;
        }
        for (int off = 32; off; off >>= 1) {
            u64 o = __shfl_xor(best, off, 64);
            if (o < best) best = o;
        }
        if (best == ~0ull) break;                    // no frontier edge
        if (lane == 0) {
            uint32_t db = (uint32_t)(best >> 24);
            int e = (int)((best >> 10) & 0x3FFF);
            int v = (int)(best & 1023);
            float dd = __uint_as_float(db);
            float s = (dd - MN) / (MX - MN) + 0.5f;  // exact reference f32 ops
            int u = src[e];
            inc[v >> 5] |= 1u << (v & 31);
            members[s_nmem++] = v;
            selU[i * 8 + cnt] = u;
            selV[i * 8 + cnt] = v;
            selS[i * 8 + cnt] = s;
            s_tot += s;                              // f32, same order as reference
        }
        cnt++;
        __syncthreads();
    }
    __syncthreads();
    if (lane == 0) {
        selCnt[i] = cnt;
        u64 h = 1469598103934665603ull;
        for (int w = 0; w < 32; ++w) { h ^= inc[w]; h *= 1099511628211ull; }
        sig[i] = h;
        // pack dup candidates: members v<i (<=6), 10 bits each, count in low 4
        u64 d = 0; int nc = 0;
        for (int k = 1; k < s_nmem; ++k) {
            int v = members[k];
            if (v < i) { d |= ((u64)(uint32_t)v) << (4 + 10 * nc); ++nc; }
        }
        dc64[i] = d | (u64)nc;
    }
    if (lane < 32) masks[(size_t)i * 32 + lane] = inc[lane];
    // unfiltered maskT scatter: members are {i} ∪ selV
    if (lane < s_nmem) {
        int n = members[lane];
        atomicOr(&maskT[(size_t)n * 32 + (i >> 5)], 1u << (i & 31));
    }
}

// ---- K3: dedup-in-place + all four outputs, one block per row i ----
// keep[j] = no member v<j of cluster_j with sig[v]==sig[j]
__global__ void k_rows(const float* __restrict__ x, const int* __restrict__ deg,
                       const u64* __restrict__ slots,
                       const uint32_t* __restrict__ masks, const uint32_t* __restrict__ maskT,
                       const u64* __restrict__ sig, const u64* __restrict__ dc64,
                       const int* __restrict__ selU, const int* __restrict__ selV,
                       const float* __restrict__ selS, const int* __restrict__ selCnt,
                       float* __restrict__ outAdj, float* __restrict__ outAs,
                       float* __restrict__ outNsm, float* __restrict__ outX) {
    __shared__ u64 sigL[NN];
    __shared__ uint32_t keepb[32];
    __shared__ uint32_t R[32], MI[32], orow[32];
    __shared__ uint32_t part[8][32];
    __shared__ int su[8], ssv[8];
    __shared__ float ss[8];
    __shared__ int s_c;
    int i = blockIdx.x, t = threadIdx.x;

    for (int j = t; j < NN; j += 256) sigL[j] = sig[j];
    if (t < 32) { keepb[t] = 0; R[t] = 0; MI[t] = masks[(size_t)i * 32 + t]; }
    if (t == 0) s_c = selCnt[i];
    if (t < 8) { su[t] = selU[i*8+t]; ssv[t] = selV[i*8+t]; ss[t] = selS[i*8+t]; }
    __syncthreads();

    // keep bits: 1 dc64 load per j (coalesced), sig compares from LDS
    for (int q = 0; q < 4; ++q) {
        int j = t + q * 256;
        u64 d = dc64[j];
        int cj = (int)(d & 15);
        u64 sj = sigL[j];
        bool dup = false;
        for (int k = 0; k < cj; ++k) {
            int v = (int)((d >> (4 + 10 * k)) & 1023);
            if (sigL[v] == sj) { dup = true; break; }
        }
        if (!dup) atomicOr(&keepb[j >> 5], 1u << (j & 31));
    }

    // R = nodes reachable by one edge from cluster i (from slot lists)
    int c = s_c;
    for (int m = 0; m <= c; ++m) {
        int u = (m == 0) ? i : ssv[m - 1];
        int dc = min(deg[u * DSTR], CAP);
        const u64* sl = slots + (size_t)u * CAP;
        for (int k = t; k < dc; k += 256) {
            int v = (int)(sl[k] & 1023);
            atomicOr(&R[v >> 5], 1u << (v & 31));
        }
    }
    __syncthreads();
    int kp = (keepb[i >> 5] >> (i & 31)) & 1;

    // orow = OR over set bits n of R of maskT[n] (8 groups x 32 lanes), 2-way unrolled
    int g = t >> 5, l = t & 31;
    uint32_t acc = 0;
    if (kp) {
        for (int wi = g; wi < 32; wi += 8) {
            uint32_t bits = R[wi];
            while (bits) {
                int b0 = __ffs(bits) - 1; bits &= bits - 1;
                uint32_t v0 = maskT[((size_t)(wi * 32 + b0)) * 32 + l];
                if (bits) {
                    int b1 = __ffs(bits) - 1; bits &= bits - 1;
                    v0 |= maskT[((size_t)(wi * 32 + b1)) * 32 + l];
                }
                acc |= v0;
            }
        }
    }
    part[g][l] = acc;
    __syncthreads();
    if (t < 32) {
        uint32_t o = 0;
        for (int gg = 0; gg < 8; ++gg) o |= part[gg][t];
        orow[t] = o & keepb[t];                      // filter by keep[j]
    }
    __syncthreads();

    // ---- writes: thread t owns j0 = 4t..4t+3 (float4, fully coalesced) ----
    int j0 = t * 4;
    int w = j0 >> 5, sh = j0 & 31;
    float4 vadj = {0,0,0,0}, vas = {0,0,0,0}, vnsm = {0,0,0,0};
    if (kp) {
        uint32_t ob = orow[w] >> sh;
        uint32_t mb = MI[w] >> sh;
        vadj.x = ((ob     ) & 1) && (j0     != i) ? 1.0f : 0.0f;
        vadj.y = ((ob >> 1) & 1) && (j0 + 1 != i) ? 1.0f : 0.0f;
        vadj.z = ((ob >> 2) & 1) && (j0 + 2 != i) ? 1.0f : 0.0f;
        vadj.w = ((ob >> 3) & 1) && (j0 + 3 != i) ? 1.0f : 0.0f;
        vas.x = (mb      & 1) ? 1.0f : 0.0f;
        vas.y = ((mb>>1) & 1) ? 1.0f : 0.0f;
        vas.z = ((mb>>2) & 1) ? 1.0f : 0.0f;
        vas.w = ((mb>>3) & 1) ? 1.0f : 0.0f;
        for (int k = 0; k < c; ++k) {
            float h = ss[k] * 0.5f;
            int u = su[k], v = ssv[k];
            vnsm.x += ((u == j0    ) ? h : 0.0f) + ((v == j0    ) ? h : 0.0f);
            vnsm.y += ((u == j0 + 1) ? h : 0.0f) + ((v == j0 + 1) ? h : 0.0f);
            vnsm.z += ((u == j0 + 2) ? h : 0.0f) + ((v == j0 + 2) ? h : 0.0f);
            vnsm.w += ((u == j0 + 3) ? h : 0.0f) + ((v == j0 + 3) ? h : 0.0f);
        }
    }
    ((float4*)outAdj)[(size_t)i * (NN/4) + t] = vadj;
    ((float4*)outAs )[(size_t)i * (NN/4) + t] = vas;
    ((float4*)outNsm)[(size_t)i * (NN/4) + t] = vnsm;

    // ---- x_new row i: thread t = feature dim ----
    float accx = 0.0f;
    if (kp) {
        for (int k = 0; k < c; ++k) {
            float h = ss[k] * 0.5f;
            accx += h * x[(size_t)su[k] * DF + t];
            accx += h * x[(size_t)ssv[k] * DF + t];
        }
    }
    outX[(size_t)i * DF + t] = accx;
}

extern "C" void kernel_launch(void* const* d_in, const int* in_sizes, int n_in,
                              void* d_out, int out_size, void* d_ws, size_t ws_size,
                              hipStream_t stream) {
    const float* x = (const float*)d_in[0];
    const int* ei = (const int*)d_in[1];
    const int* src = ei;
    const int* dst = ei + NE;

    float* out = (float*)d_out;
    float* out_adj = out;                                  // N*N
    float* out_x   = out + (size_t)NN * NN;                // N*D
    float* out_as  = out_x + (size_t)NN * DF;              // N*N
    float* out_nsm = out_as + (size_t)NN * NN;             // N*N

    char* w = (char*)d_ws;
    u64*      slots = (u64*)w;       w += (size_t)NN * CAP * 8;   // 8B-aligned first
    u64*      sig   = (u64*)w;       w += (size_t)NN * 8;
    u64*      dc64  = (u64*)w;       w += (size_t)NN * 8;
    // ---- zeroed-by-k_zero region (contiguous, 192KB): deg(padded), maskT ----
    int*      deg   = (int*)w;       w += (size_t)NN * DSTR * 4;
    uint32_t* maskT = (uint32_t*)w;  w += (size_t)NN * 32 * 4;
    // ---- end zeroed region ----
    uint32_t* pmin  = (uint32_t*)w;  w += (size_t)NB2 * 4;
    uint32_t* pmax  = (uint32_t*)w;  w += (size_t)NB2 * 4;
    uint32_t* masks = (uint32_t*)w;  w += (size_t)NN * 32 * 4;
    int*      selU  = (int*)w;       w += (size_t)NN * 8 * 4;
    int*      selV  = (int*)w;       w += (size_t)NN * 8 * 4;
    float*    selS  = (float*)w;     w += (size_t)NN * 8 * 4;
    int*      selCnt= (int*)w;       w += (size_t)NN * 4;

    // (NN*DSTR + NN*32) * 4 B = 192 KB = 48 blocks * 256 threads * 16 B
    k_zero<<<48, 256, 0, stream>>>((uint4*)deg);
    k_dist_build<<<NB2, 256, 0, stream>>>(x, src, dst, deg, slots, pmin, pmax);
    k_search<<<NN, 64, 0, stream>>>(deg, slots, pmin, pmax, src,
                                    masks, maskT, selU, selV, selS, selCnt, sig, dc64);
    k_rows<<<NN, 256, 0, stream>>>(x, deg, slots, masks, maskT, sig, dc64,
                                   selU, selV, selS, selCnt,
                                   out_adj, out_as, out_nsm, out_x);
}

// Round 13
// 34.654 us; speedup vs baseline: 1.0058x; 1.0058x over previous
//
#include <hip/hip_runtime.h>
#include <cstdint>

#define NN 1024      // nodes
#define NE 16384     // edges
#define DF 256       // features
#define UB 2.0f      // upper bound
#define MAXSEL 6
#define CAP 128      // slot capacity per node (max degree ~40 for this input)
#define NB2 1024     // k_dist_build blocks (16 edges per block)
#define DSTR 16      // deg stride: 1 word per 64B line

typedef unsigned long long u64;

// ---- K0: zero deg (padded) + maskT (192KB, contiguous) ----
__global__ void k_zero(uint4* __restrict__ p) {
    p[blockIdx.x * 256 + threadIdx.x] = make_uint4(0, 0, 0, 0);
}

// ---- K1: per-edge L2 distance + slotted lists + block min/max ----
// 16 lanes per edge (4 float4 loads each), 4 edges per wave, 16 per block.
// Butterfly reduce (xor 1,2,4,8) gives every lane its edge's full sum; two
// more butterflies (16,32) give the wave min/max of the 4 edges' dist bits.
// Slot key packs (distbits:32 | edge_id:14 | dst:10): u64 ordering == ordering
// by (dist, edge_id) == (score, edge_id) since score is monotone affine in dist.
__global__ void k_dist_build(const float* __restrict__ x, const int* __restrict__ src,
                             const int* __restrict__ dst, int* __restrict__ deg,
                             u64* __restrict__ slots,
                             uint32_t* __restrict__ pmin, uint32_t* __restrict__ pmax) {
    __shared__ uint32_t smin[4], smax[4];
    int t = threadIdx.x;
    int wid = t >> 6, lane = t & 63;
    int c16 = lane & 15;
    int e = blockIdx.x * 16 + wid * 4 + (lane >> 4);
    int u = src[e], v = dst[e];
    const float4* xa = (const float4*)(x + (size_t)u * DF);
    const float4* xb = (const float4*)(x + (size_t)v * DF);
    float4 a0 = xa[c16],      b0 = xb[c16];
    float4 a1 = xa[c16 + 16], b1 = xb[c16 + 16];
    float4 a2 = xa[c16 + 32], b2 = xb[c16 + 32];
    float4 a3 = xa[c16 + 48], b3 = xb[c16 + 48];
    double s = 0.0;
    {
        float d;
        d = a0.x-b0.x; s += (double)d*d;  d = a0.y-b0.y; s += (double)d*d;
        d = a0.z-b0.z; s += (double)d*d;  d = a0.w-b0.w; s += (double)d*d;
        d = a1.x-b1.x; s += (double)d*d;  d = a1.y-b1.y; s += (double)d*d;
        d = a1.z-b1.z; s += (double)d*d;  d = a1.w-b1.w; s += (double)d*d;
        d = a2.x-b2.x; s += (double)d*d;  d = a2.y-b2.y; s += (double)d*d;
        d = a2.z-b2.z; s += (double)d*d;  d = a2.w-b2.w; s += (double)d*d;
        d = a3.x-b3.x; s += (double)d*d;  d = a3.y-b3.y; s += (double)d*d;
        d = a3.z-b3.z; s += (double)d*d;  d = a3.w-b3.w; s += (double)d*d;
    }
    s += __shfl_xor(s, 1, 64);
    s += __shfl_xor(s, 2, 64);
    s += __shfl_xor(s, 4, 64);
    s += __shfl_xor(s, 8, 64);                    // all 16 lanes hold edge sum
    uint32_t db = __float_as_uint(sqrtf((float)s));
    if (c16 == 0) {                               // 4 lanes: one per edge
        int pos = atomicAdd(&deg[u * DSTR], 1);
        if (pos < CAP)
            slots[(size_t)u * CAP + pos] =
                ((u64)db << 24) | ((u64)(uint32_t)e << 10) | (u64)(uint32_t)v;
    }
    uint32_t mnv = db, mxv = db;
    uint32_t o;
    o = (uint32_t)__shfl_xor((int)mnv, 16, 64); mnv = min(mnv, o);
    o = (uint32_t)__shfl_xor((int)mnv, 32, 64); mnv = min(mnv, o);
    o = (uint32_t)__shfl_xor((int)mxv, 16, 64); mxv = max(mxv, o);
    o = (uint32_t)__shfl_xor((int)mxv, 32, 64); mxv = max(mxv, o);
    if (lane == 0) { smin[wid] = mnv; smax[wid] = mxv; }
    __syncthreads();
    if (t == 0) {
        pmin[blockIdx.x] = min(min(smin[0], smin[1]), min(smin[2], smin[3]));
        pmax[blockIdx.x] = max(max(smax[0], smax[1]), max(smax[2], smax[3]));
    }
}

// ---- K2: greedy cluster search, 1 wave per seed ----
// degL prefetch (parallel) + flattened member scan: all slot loads independent.
// Also writes sig, masks, unfiltered maskT scatter, and dc64 (packed dup
// candidates: members v<i, for k_rows' dedup — 1 load/j instead of ~7).
__global__ void k_search(const int* __restrict__ deg, const u64* __restrict__ slots,
                         const uint32_t* __restrict__ pmin, const uint32_t* __restrict__ pmax,
                         const int* __restrict__ src,
                         uint32_t* __restrict__ masks, uint32_t* __restrict__ maskT,
                         int* __restrict__ selU, int* __restrict__ selV,
                         float* __restrict__ selS, int* __restrict__ selCnt,
                         u64* __restrict__ sig, u64* __restrict__ dc64) {
    __shared__ uint32_t inc[32];
    __shared__ int members[8];
    __shared__ int degL[8], offL[9];
    __shared__ float s_tot;
    __shared__ int s_nmem;
    int i = blockIdx.x, lane = threadIdx.x;
    if (lane < 32) inc[lane] = 0;

    // reduce 1024 block partials -> MN, MX (uint4 loads, 4 iters/lane)
    uint32_t mnb = 0xFFFFFFFFu, mxb = 0u;
    const uint4* p4n = (const uint4*)pmin;
    const uint4* p4x = (const uint4*)pmax;
    for (int k = lane; k < NB2 / 4; k += 64) {
        uint4 a = p4n[k], b = p4x[k];
        mnb = min(mnb, min(min(a.x, a.y), min(a.z, a.w)));
        mxb = max(mxb, max(max(b.x, b.y), max(b.z, b.w)));
    }
    for (int off = 32; off; off >>= 1) {
        uint32_t oa = (uint32_t)__shfl_xor((int)mnb, off, 64);
        uint32_t ob = (uint32_t)__shfl_xor((int)mxb, off, 64);
        mnb = min(mnb, oa);
        mxb = max(mxb, ob);
    }
    float MN = __uint_as_float(mnb);
    float MX = __uint_as_float(mxb);

    if (lane == 0) {
        inc[i >> 5] = 1u << (i & 31);
        members[0] = i;
        s_tot = 0.0f;
        s_nmem = 1;
    }
    __syncthreads();
    int cnt = 0;
    for (int step = 0; step < MAXSEL; ++step) {
        if (s_tot >= UB) break;                      // uniform LDS scalar
        int nm = s_nmem;
        if (lane < nm) degL[lane] = min(deg[members[lane] * DSTR], CAP);
        __syncthreads();
        if (lane == 0) {
            offL[0] = 0;
            for (int m = 0; m < nm; ++m) offL[m + 1] = offL[m] + degL[m];
        }
        __syncthreads();
        int T = offL[nm];
        u64 best = ~0ull;
        for (int f = lane; f < T; f += 64) {
            int m = 0;
            while (f >= offL[m + 1]) ++m;            // <=7 LDS iters
            u64 en = slots[(size_t)members[m] * CAP + (f - offL[m])];
            int v = (int)(en & 1023);
            if (!((inc[v >> 5] >> (v & 31)) & 1u) && en < best) best = en;
        }
        for (int off = 32; off; off >>= 1) {
            u64 o = __shfl_xor(best, off, 64);
            if (o < best) best = o;
        }
        if (best == ~0ull) break;                    // no frontier edge
        if (lane == 0) {
            uint32_t db = (uint32_t)(best >> 24);
            int e = (int)((best >> 10) & 0x3FFF);
            int v = (int)(best & 1023);
            float dd = __uint_as_float(db);
            float s = (dd - MN) / (MX - MN) + 0.5f;  // exact reference f32 ops
            int u = src[e];
            inc[v >> 5] |= 1u << (v & 31);
            members[s_nmem++] = v;
            selU[i * 8 + cnt] = u;
            selV[i * 8 + cnt] = v;
            selS[i * 8 + cnt] = s;
            s_tot += s;                              // f32, same order as reference
        }
        cnt++;
        __syncthreads();
    }
    __syncthreads();
    if (lane == 0) {
        selCnt[i] = cnt;
        u64 h = 1469598103934665603ull;
        for (int w = 0; w < 32; ++w) { h ^= inc[w]; h *= 1099511628211ull; }
        sig[i] = h;
        // pack dup candidates: members v<i (<=6), 10 bits each, count in low 4
        u64 d = 0; int nc = 0;
        for (int k = 1; k < s_nmem; ++k) {
            int v = members[k];
            if (v < i) { d |= ((u64)(uint32_t)v) << (4 + 10 * nc); ++nc; }
        }
        dc64[i] = d | (u64)nc;
    }
    if (lane < 32) masks[(size_t)i * 32 + lane] = inc[lane];
    // unfiltered maskT scatter: members are {i} ∪ selV
    if (lane < s_nmem) {
        int n = members[lane];
        atomicOr(&maskT[(size_t)n * 32 + (i >> 5)], 1u << (i & 31));
    }
}

// ---- K3: dedup-in-place + all four outputs, one block per row i ----
// keep[j] = no member v<j of cluster_j with sig[v]==sig[j]
__global__ void k_rows(const float* __restrict__ x, const int* __restrict__ deg,
                       const u64* __restrict__ slots,
                       const uint32_t* __restrict__ masks, const uint32_t* __restrict__ maskT,
                       const u64* __restrict__ sig, const u64* __restrict__ dc64,
                       const int* __restrict__ selU, const int* __restrict__ selV,
                       const float* __restrict__ selS, const int* __restrict__ selCnt,
                       float* __restrict__ outAdj, float* __restrict__ outAs,
                       float* __restrict__ outNsm, float* __restrict__ outX) {
    __shared__ u64 sigL[NN];
    __shared__ uint32_t keepb[32];
    __shared__ uint32_t R[32], MI[32], orow[32];
    __shared__ uint32_t part[8][32];
    __shared__ int su[8], ssv[8];
    __shared__ float ss[8];
    __shared__ int s_c;
    int i = blockIdx.x, t = threadIdx.x;

    for (int j = t; j < NN; j += 256) sigL[j] = sig[j];
    if (t < 32) { keepb[t] = 0; R[t] = 0; MI[t] = masks[(size_t)i * 32 + t]; }
    if (t == 0) s_c = selCnt[i];
    if (t < 8) { su[t] = selU[i*8+t]; ssv[t] = selV[i*8+t]; ss[t] = selS[i*8+t]; }
    __syncthreads();

    // keep bits: 1 dc64 load per j (coalesced), sig compares from LDS
    for (int q = 0; q < 4; ++q) {
        int j = t + q * 256;
        u64 d = dc64[j];
        int cj = (int)(d & 15);
        u64 sj = sigL[j];
        bool dup = false;
        for (int k = 0; k < cj; ++k) {
            int v = (int)((d >> (4 + 10 * k)) & 1023);
            if (sigL[v] == sj) { dup = true; break; }
        }
        if (!dup) atomicOr(&keepb[j >> 5], 1u << (j & 31));
    }

    // R = nodes reachable by one edge from cluster i (from slot lists)
    int c = s_c;
    for (int m = 0; m <= c; ++m) {
        int u = (m == 0) ? i : ssv[m - 1];
        int dc = min(deg[u * DSTR], CAP);
        const u64* sl = slots + (size_t)u * CAP;
        for (int k = t; k < dc; k += 256) {
            int v = (int)(sl[k] & 1023);
            atomicOr(&R[v >> 5], 1u << (v & 31));
        }
    }
    __syncthreads();
    int kp = (keepb[i >> 5] >> (i & 31)) & 1;

    // orow = OR over set bits n of R of maskT[n] (8 groups x 32 lanes), 2-way unrolled
    int g = t >> 5, l = t & 31;
    uint32_t acc = 0;
    if (kp) {
        for (int wi = g; wi < 32; wi += 8) {
            uint32_t bits = R[wi];
            while (bits) {
                int b0 = __ffs(bits) - 1; bits &= bits - 1;
                uint32_t v0 = maskT[((size_t)(wi * 32 + b0)) * 32 + l];
                if (bits) {
                    int b1 = __ffs(bits) - 1; bits &= bits - 1;
                    v0 |= maskT[((size_t)(wi * 32 + b1)) * 32 + l];
                }
                acc |= v0;
            }
        }
    }
    part[g][l] = acc;
    __syncthreads();
    if (t < 32) {
        uint32_t o = 0;
        for (int gg = 0; gg < 8; ++gg) o |= part[gg][t];
        orow[t] = o & keepb[t];                      // filter by keep[j]
    }
    __syncthreads();

    // ---- writes: thread t owns j0 = 4t..4t+3 (float4, fully coalesced) ----
    int j0 = t * 4;
    int w = j0 >> 5, sh = j0 & 31;
    float4 vadj = {0,0,0,0}, vas = {0,0,0,0}, vnsm = {0,0,0,0};
    if (kp) {
        uint32_t ob = orow[w] >> sh;
        uint32_t mb = MI[w] >> sh;
        vadj.x = ((ob     ) & 1) && (j0     != i) ? 1.0f : 0.0f;
        vadj.y = ((ob >> 1) & 1) && (j0 + 1 != i) ? 1.0f : 0.0f;
        vadj.z = ((ob >> 2) & 1) && (j0 + 2 != i) ? 1.0f : 0.0f;
        vadj.w = ((ob >> 3) & 1) && (j0 + 3 != i) ? 1.0f : 0.0f;
        vas.x = (mb      & 1) ? 1.0f : 0.0f;
        vas.y = ((mb>>1) & 1) ? 1.0f : 0.0f;
        vas.z = ((mb>>2) & 1) ? 1.0f : 0.0f;
        vas.w = ((mb>>3) & 1) ? 1.0f : 0.0f;
        for (int k = 0; k < c; ++k) {
            float h = ss[k] * 0.5f;
            int u = su[k], v = ssv[k];
            vnsm.x += ((u == j0    ) ? h : 0.0f) + ((v == j0    ) ? h : 0.0f);
            vnsm.y += ((u == j0 + 1) ? h : 0.0f) + ((v == j0 + 1) ? h : 0.0f);
            vnsm.z += ((u == j0 + 2) ? h : 0.0f) + ((v == j0 + 2) ? h : 0.0f);
            vnsm.w += ((u == j0 + 3) ? h : 0.0f) + ((v == j0 + 3) ? h : 0.0f);
        }
    }
    ((float4*)outAdj)[(size_t)i * (NN/4) + t] = vadj;
    ((float4*)outAs )[(size_t)i * (NN/4) + t] = vas;
    ((float4*)outNsm)[(size_t)i * (NN/4) + t] = vnsm;

    // ---- x_new row i: thread t = feature dim ----
    float accx = 0.0f;
    if (kp) {
        for (int k = 0; k < c; ++k) {
            float h = ss[k] * 0.5f;
            accx += h * x[(size_t)su[k] * DF + t];
            accx += h * x[(size_t)ssv[k] * DF + t];
        }
    }
    outX[(size_t)i * DF + t] = accx;
}

extern "C" void kernel_launch(void* const* d_in, const int* in_sizes, int n_in,
                              void* d_out, int out_size, void* d_ws, size_t ws_size,
                              hipStream_t stream) {
    const float* x = (const float*)d_in[0];
    const int* ei = (const int*)d_in[1];
    const int* src = ei;
    const int* dst = ei + NE;

    float* out = (float*)d_out;
    float* out_adj = out;                                  // N*N
    float* out_x   = out + (size_t)NN * NN;                // N*D
    float* out_as  = out_x + (size_t)NN * DF;              // N*N
    float* out_nsm = out_as + (size_t)NN * NN;             // N*N

    char* w = (char*)d_ws;
    u64*      slots = (u64*)w;       w += (size_t)NN * CAP * 8;   // 8B-aligned first
    u64*      sig   = (u64*)w;       w += (size_t)NN * 8;
    u64*      dc64  = (u64*)w;       w += (size_t)NN * 8;
    // ---- zeroed-by-k_zero region (contiguous, 192KB): deg(padded), maskT ----
    int*      deg   = (int*)w;       w += (size_t)NN * DSTR * 4;
    uint32_t* maskT = (uint32_t*)w;  w += (size_t)NN * 32 * 4;
    // ---- end zeroed region ----
    uint32_t* pmin  = (uint32_t*)w;  w += (size_t)NB2 * 4;
    uint32_t* pmax  = (uint32_t*)w;  w += (size_t)NB2 * 4;
    uint32_t* masks = (uint32_t*)w;  w += (size_t)NN * 32 * 4;
    int*      selU  = (int*)w;       w += (size_t)NN * 8 * 4;
    int*      selV  = (int*)w;       w += (size_t)NN * 8 * 4;
    float*    selS  = (float*)w;     w += (size_t)NN * 8 * 4;
    int*      selCnt= (int*)w;       w += (size_t)NN * 4;

    // (NN*DSTR + NN*32) * 4 B = 192 KB = 48 blocks * 256 threads * 16 B
    k_zero<<<48, 256, 0, stream>>>((uint4*)deg);
    k_dist_build<<<NB2, 256, 0, stream>>>(x, src, dst, deg, slots, pmin, pmax);
    k_search<<<NN, 64, 0, stream>>>(deg, slots, pmin, pmax, src,
                                    masks, maskT, selU, selV, selS, selCnt, sig, dc64);
    k_rows<<<NN, 256, 0, stream>>>(x, deg, slots, masks, maskT, sig, dc64,
                                   selU, selV, selS, selCnt,
                                   out_adj, out_as, out_nsm, out_x);
}

// Round 14
// 33.767 us; speedup vs baseline: 1.0322x; 1.0263x over previous
//
#include <hip/hip_runtime.h>
#include <cstdint>

#define NN 1024      // nodes
#define NE 16384     // edges
#define DF 256       // features
#define UB 2.0f      // upper bound
#define MAXSEL 6
#define CAP 64       // slot capacity per node (Poisson(16): P(deg>64) ~ 1e-20)
#define NB2 1024     // k_dist_build blocks (16 edges per block)
#define DSTR 16      // deg stride: 1 word per 64B line
#define FILLB 176    // 128 blocks sentinel-fill slots (512KB) + 48 blocks zero deg+maskT (192KB)

typedef unsigned long long u64;

// ---- K0: fill slots with ~0 sentinel, zero deg+maskT (contiguous regions) ----
__global__ void k_fill(uint4* __restrict__ p) {
    uint32_t v = (blockIdx.x < 128) ? 0xFFFFFFFFu : 0u;
    p[blockIdx.x * 256 + threadIdx.x] = make_uint4(v, v, v, v);
}

// ---- K1: per-edge L2 distance + slotted lists + block min/max ----
// 16 lanes per edge (4 float4 loads each), 4 edges per wave, 16 per block.
// Slot key packs (distbits:32 | edge_id:14 | dst:10): u64 ordering == ordering
// by (dist, edge_id) == (score, edge_id) since score is monotone affine in dist.
__global__ void k_dist_build(const float* __restrict__ x, const int* __restrict__ src,
                             const int* __restrict__ dst, int* __restrict__ deg,
                             u64* __restrict__ slots,
                             uint32_t* __restrict__ pmin, uint32_t* __restrict__ pmax) {
    __shared__ uint32_t smin[4], smax[4];
    int t = threadIdx.x;
    int wid = t >> 6, lane = t & 63;
    int c16 = lane & 15;
    int e = blockIdx.x * 16 + wid * 4 + (lane >> 4);
    int u = src[e], v = dst[e];
    const float4* xa = (const float4*)(x + (size_t)u * DF);
    const float4* xb = (const float4*)(x + (size_t)v * DF);
    float4 a0 = xa[c16],      b0 = xb[c16];
    float4 a1 = xa[c16 + 16], b1 = xb[c16 + 16];
    float4 a2 = xa[c16 + 32], b2 = xb[c16 + 32];
    float4 a3 = xa[c16 + 48], b3 = xb[c16 + 48];
    double s = 0.0;
    {
        float d;
        d = a0.x-b0.x; s += (double)d*d;  d = a0.y-b0.y; s += (double)d*d;
        d = a0.z-b0.z; s += (double)d*d;  d = a0.w-b0.w; s += (double)d*d;
        d = a1.x-b1.x; s += (double)d*d;  d = a1.y-b1.y; s += (double)d*d;
        d = a1.z-b1.z; s += (double)d*d;  d = a1.w-b1.w; s += (double)d*d;
        d = a2.x-b2.x; s += (double)d*d;  d = a2.y-b2.y; s += (double)d*d;
        d = a2.z-b2.z; s += (double)d*d;  d = a2.w-b2.w; s += (double)d*d;
        d = a3.x-b3.x; s += (double)d*d;  d = a3.y-b3.y; s += (double)d*d;
        d = a3.z-b3.z; s += (double)d*d;  d = a3.w-b3.w; s += (double)d*d;
    }
    s += __shfl_xor(s, 1, 64);
    s += __shfl_xor(s, 2, 64);
    s += __shfl_xor(s, 4, 64);
    s += __shfl_xor(s, 8, 64);                    // all 16 lanes hold edge sum
    uint32_t db = __float_as_uint(sqrtf((float)s));
    if (c16 == 0) {                               // 4 lanes: one per edge
        int pos = atomicAdd(&deg[u * DSTR], 1);
        if (pos < CAP)
            slots[(size_t)u * CAP + pos] =
                ((u64)db << 24) | ((u64)(uint32_t)e << 10) | (u64)(uint32_t)v;
    }
    uint32_t mnv = db, mxv = db;
    uint32_t o;
    o = (uint32_t)__shfl_xor((int)mnv, 16, 64); mnv = min(mnv, o);
    o = (uint32_t)__shfl_xor((int)mnv, 32, 64); mnv = min(mnv, o);
    o = (uint32_t)__shfl_xor((int)mxv, 16, 64); mxv = max(mxv, o);
    o = (uint32_t)__shfl_xor((int)mxv, 32, 64); mxv = max(mxv, o);
    if (lane == 0) { smin[wid] = mnv; smax[wid] = mxv; }
    __syncthreads();
    if (t == 0) {
        pmin[blockIdx.x] = min(min(smin[0], smin[1]), min(smin[2], smin[3]));
        pmax[blockIdx.x] = max(max(smax[0], smax[1]), max(smax[2], smax[3]));
    }
}

// ---- K2: greedy cluster search, 1 wave per seed, LDS slot pool ----
// Each new member costs ONE independent 64-lane slot gather; all min-scans run
// from LDS. Sentinel ~0ull entries can never win (en < best is false).
__global__ void k_search(const u64* __restrict__ slots,
                         const uint32_t* __restrict__ pmin, const uint32_t* __restrict__ pmax,
                         const int* __restrict__ src,
                         uint32_t* __restrict__ masks, uint32_t* __restrict__ maskT,
                         int* __restrict__ selU, int* __restrict__ selV,
                         float* __restrict__ selS, int* __restrict__ selCnt,
                         u64* __restrict__ sig, u64* __restrict__ dc64) {
    __shared__ u64 pool[8][64];
    __shared__ uint32_t inc[32];
    __shared__ int members[8];
    __shared__ float s_tot;
    __shared__ int s_nmem;
    int i = blockIdx.x, lane = threadIdx.x;
    if (lane < 32) inc[lane] = 0;

    // reduce 1024 block partials -> MN, MX (uint4 loads, 4 iters/lane)
    uint32_t mnb = 0xFFFFFFFFu, mxb = 0u;
    const uint4* p4n = (const uint4*)pmin;
    const uint4* p4x = (const uint4*)pmax;
    for (int k = lane; k < NB2 / 4; k += 64) {
        uint4 a = p4n[k], b = p4x[k];
        mnb = min(mnb, min(min(a.x, a.y), min(a.z, a.w)));
        mxb = max(mxb, max(max(b.x, b.y), max(b.z, b.w)));
    }
    for (int off = 32; off; off >>= 1) {
        uint32_t oa = (uint32_t)__shfl_xor((int)mnb, off, 64);
        uint32_t ob = (uint32_t)__shfl_xor((int)mxb, off, 64);
        mnb = min(mnb, oa);
        mxb = max(mxb, ob);
    }
    float MN = __uint_as_float(mnb);
    float MX = __uint_as_float(mxb);

    if (lane == 0) {
        inc[i >> 5] = 1u << (i & 31);
        members[0] = i;
        s_tot = 0.0f;
        s_nmem = 1;
    }
    pool[0][lane] = slots[(size_t)i * CAP + lane];   // seed's slots -> pool row 0
    __syncthreads();
    int cnt = 0;
    for (int step = 0; step < MAXSEL; ++step) {
        if (s_tot >= UB) break;                      // uniform LDS scalar
        int nm = s_nmem;
        u64 best = ~0ull;
        #pragma unroll
        for (int m = 0; m < 8; ++m) {
            if (m < nm) {
                u64 en = pool[m][lane];
                int v = (int)(en & 1023);
                if (!((inc[v >> 5] >> (v & 31)) & 1u) && en < best) best = en;
            }
        }
        for (int off = 32; off; off >>= 1) {
            u64 o = __shfl_xor(best, off, 64);
            if (o < best) best = o;
        }
        if (best == ~0ull) break;                    // no frontier edge
        if (lane == 0) {
            uint32_t db = (uint32_t)(best >> 24);
            int e = (int)((best >> 10) & 0x3FFF);
            int v = (int)(best & 1023);
            float dd = __uint_as_float(db);
            float s = (dd - MN) / (MX - MN) + 0.5f;  // exact reference f32 ops
            inc[v >> 5] |= 1u << (v & 31);
            members[s_nmem++] = v;
            selU[i * 8 + cnt] = src[e];
            selV[i * 8 + cnt] = v;
            selS[i * 8 + cnt] = s;
            s_tot += s;                              // f32, same order as reference
        }
        cnt++;
        __syncthreads();
        int newm = s_nmem - 1;                       // fetch new member's slots
        pool[newm][lane] = slots[(size_t)members[newm] * CAP + lane];
        __syncthreads();
    }
    __syncthreads();
    if (lane == 0) {
        selCnt[i] = cnt;
        u64 h = 1469598103934665603ull;
        for (int w = 0; w < 32; ++w) { h ^= inc[w]; h *= 1099511628211ull; }
        sig[i] = h;
        // pack dup candidates: members v<i (<=6), 10 bits each, count in low 4
        u64 d = 0; int nc = 0;
        for (int k = 1; k < s_nmem; ++k) {
            int v = members[k];
            if (v < i) { d |= ((u64)(uint32_t)v) << (4 + 10 * nc); ++nc; }
        }
        dc64[i] = d | (u64)nc;
    }
    if (lane < 32) masks[(size_t)i * 32 + lane] = inc[lane];
    // unfiltered maskT scatter: members are {i} ∪ selV
    if (lane < s_nmem) {
        int n = members[lane];
        atomicOr(&maskT[(size_t)n * 32 + (i >> 5)], 1u << (i & 31));
    }
}

// ---- K3: dedup-in-place + all four outputs, one block per row i ----
// keep[j] = no member v<j of cluster_j with sig[v]==sig[j]
__global__ void k_rows(const float* __restrict__ x, const u64* __restrict__ slots,
                       const uint32_t* __restrict__ masks, const uint32_t* __restrict__ maskT,
                       const u64* __restrict__ sig, const u64* __restrict__ dc64,
                       const int* __restrict__ selU, const int* __restrict__ selV,
                       const float* __restrict__ selS, const int* __restrict__ selCnt,
                       float* __restrict__ outAdj, float* __restrict__ outAs,
                       float* __restrict__ outNsm, float* __restrict__ outX) {
    __shared__ u64 sigL[NN];
    __shared__ uint32_t keepb[32];
    __shared__ uint32_t R[32], MI[32], orow[32];
    __shared__ uint32_t part[8][32];
    __shared__ int list[512];
    __shared__ int s_lcnt;
    __shared__ int su[8], ssv[8];
    __shared__ float ss[8];
    __shared__ int s_c;
    int i = blockIdx.x, t = threadIdx.x;

    for (int j = t; j < NN; j += 256) sigL[j] = sig[j];
    if (t < 32) { keepb[t] = 0; R[t] = 0; MI[t] = masks[(size_t)i * 32 + t]; }
    if (t == 0) { s_c = selCnt[i]; s_lcnt = 0; }
    if (t < 8) { su[t] = selU[i*8+t]; ssv[t] = selV[i*8+t]; ss[t] = selS[i*8+t]; }
    __syncthreads();

    // keep bits: 1 dc64 load per j (coalesced), sig compares from LDS
    for (int q = 0; q < 4; ++q) {
        int j = t + q * 256;
        u64 d = dc64[j];
        int cj = (int)(d & 15);
        u64 sj = sigL[j];
        bool dup = false;
        for (int k = 0; k < cj; ++k) {
            int v = (int)((d >> (4 + 10 * k)) & 1023);
            if (sigL[v] == sj) { dup = true; break; }
        }
        if (!dup) atomicOr(&keepb[j >> 5], 1u << (j & 31));
    }

    // R = nodes reachable by one edge from cluster i — flattened independent gather
    int c = s_c;
    int total = (c + 1) * CAP;                        // <= 448
    for (int k = t; k < total; k += 256) {
        int m = k >> 6;
        int u = (m == 0) ? i : ssv[m - 1];
        u64 en = slots[(size_t)u * CAP + (k & 63)];
        if (en != ~0ull) {
            int v = (int)(en & 1023);
            atomicOr(&R[v >> 5], 1u << (v & 31));
        }
    }
    __syncthreads();
    int kp = (keepb[i >> 5] >> (i & 31)) & 1;

    // expand R's set bits into a list (independent gather loop afterwards)
    if (t < 32) {
        uint32_t bits = R[t];
        while (bits) {
            int b = __ffs(bits) - 1;
            bits &= bits - 1;
            int p = atomicAdd(&s_lcnt, 1);
            list[p] = t * 32 + b;
        }
    }
    __syncthreads();
    int lcnt = s_lcnt;

    // orow = OR over n in list of maskT[n]  (8 groups x 32 lanes, independent loads)
    int g = t >> 5, l = t & 31;
    uint32_t acc = 0;
    if (kp) {
        for (int k = g; k < lcnt; k += 8)
            acc |= maskT[(size_t)list[k] * 32 + l];   // coalesced over l
    }
    part[g][l] = acc;
    __syncthreads();
    if (t < 32) {
        uint32_t o = 0;
        for (int gg = 0; gg < 8; ++gg) o |= part[gg][t];
        orow[t] = o & keepb[t];                      // filter by keep[j]
    }
    __syncthreads();

    // ---- writes: thread t owns j0 = 4t..4t+3 (float4, fully coalesced) ----
    int j0 = t * 4;
    int w = j0 >> 5, sh = j0 & 31;
    float4 vadj = {0,0,0,0}, vas = {0,0,0,0}, vnsm = {0,0,0,0};
    if (kp) {
        uint32_t ob = orow[w] >> sh;
        uint32_t mb = MI[w] >> sh;
        vadj.x = ((ob     ) & 1) && (j0     != i) ? 1.0f : 0.0f;
        vadj.y = ((ob >> 1) & 1) && (j0 + 1 != i) ? 1.0f : 0.0f;
        vadj.z = ((ob >> 2) & 1) && (j0 + 2 != i) ? 1.0f : 0.0f;
        vadj.w = ((ob >> 3) & 1) && (j0 + 3 != i) ? 1.0f : 0.0f;
        vas.x = (mb      & 1) ? 1.0f : 0.0f;
        vas.y = ((mb>>1) & 1) ? 1.0f : 0.0f;
        vas.z = ((mb>>2) & 1) ? 1.0f : 0.0f;
        vas.w = ((mb>>3) & 1) ? 1.0f : 0.0f;
        for (int k = 0; k < c; ++k) {
            float h = ss[k] * 0.5f;
            int u = su[k], v = ssv[k];
            vnsm.x += ((u == j0    ) ? h : 0.0f) + ((v == j0    ) ? h : 0.0f);
            vnsm.y += ((u == j0 + 1) ? h : 0.0f) + ((v == j0 + 1) ? h : 0.0f);
            vnsm.z += ((u == j0 + 2) ? h : 0.0f) + ((v == j0 + 2) ? h : 0.0f);
            vnsm.w += ((u == j0 + 3) ? h : 0.0f) + ((v == j0 + 3) ? h : 0.0f);
        }
    }
    ((float4*)outAdj)[(size_t)i * (NN/4) + t] = vadj;
    ((float4*)outAs )[(size_t)i * (NN/4) + t] = vas;
    ((float4*)outNsm)[(size_t)i * (NN/4) + t] = vnsm;

    // ---- x_new row i: thread t = feature dim ----
    float accx = 0.0f;
    if (kp) {
        for (int k = 0; k < c; ++k) {
            float h = ss[k] * 0.5f;
            accx += h * x[(size_t)su[k] * DF + t];
            accx += h * x[(size_t)ssv[k] * DF + t];
        }
    }
    outX[(size_t)i * DF + t] = accx;
}

extern "C" void kernel_launch(void* const* d_in, const int* in_sizes, int n_in,
                              void* d_out, int out_size, void* d_ws, size_t ws_size,
                              hipStream_t stream) {
    const float* x = (const float*)d_in[0];
    const int* ei = (const int*)d_in[1];
    const int* src = ei;
    const int* dst = ei + NE;

    float* out = (float*)d_out;
    float* out_adj = out;                                  // N*N
    float* out_x   = out + (size_t)NN * NN;                // N*D
    float* out_as  = out_x + (size_t)NN * DF;              // N*N
    float* out_nsm = out_as + (size_t)NN * NN;             // N*N

    char* w = (char*)d_ws;
    // ---- k_fill region: slots (512KB sentinel 0xFF) | deg+maskT (192KB zeros) ----
    u64*      slots = (u64*)w;       w += (size_t)NN * CAP * 8;
    int*      deg   = (int*)w;       w += (size_t)NN * DSTR * 4;
    uint32_t* maskT = (uint32_t*)w;  w += (size_t)NN * 32 * 4;
    // ---- end k_fill region ----
    u64*      sig   = (u64*)w;       w += (size_t)NN * 8;
    u64*      dc64  = (u64*)w;       w += (size_t)NN * 8;
    uint32_t* pmin  = (uint32_t*)w;  w += (size_t)NB2 * 4;
    uint32_t* pmax  = (uint32_t*)w;  w += (size_t)NB2 * 4;
    uint32_t* masks = (uint32_t*)w;  w += (size_t)NN * 32 * 4;
    int*      selU  = (int*)w;       w += (size_t)NN * 8 * 4;
    int*      selV  = (int*)w;       w += (size_t)NN * 8 * 4;
    float*    selS  = (float*)w;     w += (size_t)NN * 8 * 4;
    int*      selCnt= (int*)w;       w += (size_t)NN * 4;

    k_fill<<<FILLB, 256, 0, stream>>>((uint4*)slots);
    k_dist_build<<<NB2, 256, 0, stream>>>(x, src, dst, deg, slots, pmin, pmax);
    k_search<<<NN, 64, 0, stream>>>(slots, pmin, pmax, src,
                                    masks, maskT, selU, selV, selS, selCnt, sig, dc64);
    k_rows<<<NN, 256, 0, stream>>>(x, slots, masks, maskT, sig, dc64,
                                   selU, selV, selS, selCnt,
                                   out_adj, out_as, out_nsm, out_x);
}

// Round 15
// 33.679 us; speedup vs baseline: 1.0350x; 1.0026x over previous
//
#include <hip/hip_runtime.h>
#include <cstdint>

#define NN 1024      // nodes
#define NE 16384     // edges
#define DF 256       // features
#define UB 2.0f      // upper bound
#define MAXSEL 6
#define CAP 64       // slot capacity per node (Poisson(16): P(deg>64) ~ 1e-20)
#define NB2 1024     // k_dist_build blocks (16 edges per block)
#define DSTR 16      // deg stride: 1 word per 64B line

typedef unsigned long long u64;

// ---- K0: zero deg (padded) + maskT (192KB contiguous) ----
__global__ void k_zero(uint4* __restrict__ p) {
    p[blockIdx.x * 256 + threadIdx.x] = make_uint4(0, 0, 0, 0);
}

// ---- K1: per-edge L2 distance + slotted lists + block min/max ----
// 16 lanes per edge (4 float4 loads each), 4 edges per wave, 16 per block.
// Slot key packs (distbits:32 | edge_id:14 | dst:10): u64 ordering == ordering
// by (dist, edge_id) == (score, edge_id) since score is monotone affine in dist.
__global__ void k_dist_build(const float* __restrict__ x, const int* __restrict__ src,
                             const int* __restrict__ dst, int* __restrict__ deg,
                             u64* __restrict__ slots,
                             uint32_t* __restrict__ pmin, uint32_t* __restrict__ pmax) {
    __shared__ uint32_t smin[4], smax[4];
    int t = threadIdx.x;
    int wid = t >> 6, lane = t & 63;
    int c16 = lane & 15;
    int e = blockIdx.x * 16 + wid * 4 + (lane >> 4);
    int u = src[e], v = dst[e];
    const float4* xa = (const float4*)(x + (size_t)u * DF);
    const float4* xb = (const float4*)(x + (size_t)v * DF);
    float4 a0 = xa[c16],      b0 = xb[c16];
    float4 a1 = xa[c16 + 16], b1 = xb[c16 + 16];
    float4 a2 = xa[c16 + 32], b2 = xb[c16 + 32];
    float4 a3 = xa[c16 + 48], b3 = xb[c16 + 48];
    double s = 0.0;
    {
        float d;
        d = a0.x-b0.x; s += (double)d*d;  d = a0.y-b0.y; s += (double)d*d;
        d = a0.z-b0.z; s += (double)d*d;  d = a0.w-b0.w; s += (double)d*d;
        d = a1.x-b1.x; s += (double)d*d;  d = a1.y-b1.y; s += (double)d*d;
        d = a1.z-b1.z; s += (double)d*d;  d = a1.w-b1.w; s += (double)d*d;
        d = a2.x-b2.x; s += (double)d*d;  d = a2.y-b2.y; s += (double)d*d;
        d = a2.z-b2.z; s += (double)d*d;  d = a2.w-b2.w; s += (double)d*d;
        d = a3.x-b3.x; s += (double)d*d;  d = a3.y-b3.y; s += (double)d*d;
        d = a3.z-b3.z; s += (double)d*d;  d = a3.w-b3.w; s += (double)d*d;
    }
    s += __shfl_xor(s, 1, 64);
    s += __shfl_xor(s, 2, 64);
    s += __shfl_xor(s, 4, 64);
    s += __shfl_xor(s, 8, 64);                    // all 16 lanes hold edge sum
    uint32_t db = __float_as_uint(sqrtf((float)s));
    if (c16 == 0) {                               // 4 lanes: one per edge
        int pos = atomicAdd(&deg[u * DSTR], 1);
        if (pos < CAP)
            slots[(size_t)u * CAP + pos] =
                ((u64)db << 24) | ((u64)(uint32_t)e << 10) | (u64)(uint32_t)v;
    }
    uint32_t mnv = db, mxv = db;
    uint32_t o;
    o = (uint32_t)__shfl_xor((int)mnv, 16, 64); mnv = min(mnv, o);
    o = (uint32_t)__shfl_xor((int)mnv, 32, 64); mnv = min(mnv, o);
    o = (uint32_t)__shfl_xor((int)mxv, 16, 64); mxv = max(mxv, o);
    o = (uint32_t)__shfl_xor((int)mxv, 32, 64); mxv = max(mxv, o);
    if (lane == 0) { smin[wid] = mnv; smax[wid] = mxv; }
    __syncthreads();
    if (t == 0) {
        pmin[blockIdx.x] = min(min(smin[0], smin[1]), min(smin[2], smin[3]));
        pmax[blockIdx.x] = max(max(smax[0], smax[1]), max(smax[2], smax[3]));
    }
}

// ---- K2: greedy cluster search, 1 wave per seed, register-uniform state ----
// Butterfly reduce leaves `best` in every lane -> all lanes decode winner and
// issue the next member's deg+slot loads immediately (overlaps lane0 updates).
// Wave-uniform scalars (tot, nmem) live in registers; one barrier per step.
// Pool entries beyond deg are written as ~0ull (can never win: en < best false).
__global__ void k_search(const int* __restrict__ deg, const u64* __restrict__ slots,
                         const uint32_t* __restrict__ pmin, const uint32_t* __restrict__ pmax,
                         const int* __restrict__ src,
                         uint32_t* __restrict__ masks, uint32_t* __restrict__ maskT,
                         int* __restrict__ selU, int* __restrict__ selV,
                         float* __restrict__ selS, int* __restrict__ selCnt,
                         u64* __restrict__ sig, u64* __restrict__ dc64) {
    __shared__ u64 pool[8][64];
    __shared__ uint32_t inc[32];
    __shared__ int members[8];
    int i = blockIdx.x, lane = threadIdx.x;
    if (lane < 32) inc[lane] = 0;

    // reduce 1024 block partials -> MN, MX (uint4 loads, 4 iters/lane)
    uint32_t mnb = 0xFFFFFFFFu, mxb = 0u;
    const uint4* p4n = (const uint4*)pmin;
    const uint4* p4x = (const uint4*)pmax;
    for (int k = lane; k < NB2 / 4; k += 64) {
        uint4 a = p4n[k], b = p4x[k];
        mnb = min(mnb, min(min(a.x, a.y), min(a.z, a.w)));
        mxb = max(mxb, max(max(b.x, b.y), max(b.z, b.w)));
    }
    for (int off = 32; off; off >>= 1) {
        uint32_t oa = (uint32_t)__shfl_xor((int)mnb, off, 64);
        uint32_t ob = (uint32_t)__shfl_xor((int)mxb, off, 64);
        mnb = min(mnb, oa);
        mxb = max(mxb, ob);
    }
    float MN = __uint_as_float(mnb);
    float MX = __uint_as_float(mxb);

    // seed row 0 (deg load + slot gather issued together, independent)
    int dv0 = deg[i * DSTR];
    u64 g0 = slots[(size_t)i * CAP + lane];
    if (lane == 0) { inc[i >> 5] = 1u << (i & 31); members[0] = i; }
    pool[0][lane] = (lane < min(dv0, CAP)) ? g0 : ~0ull;
    float tot = 0.0f;
    int nmem = 1, cnt = 0;
    __syncthreads();

    for (int step = 0; step < MAXSEL; ++step) {
        if (tot >= UB) break;                        // register-uniform
        u64 best = ~0ull;
        #pragma unroll
        for (int m = 0; m < 8; ++m) {
            if (m < nmem) {
                u64 en = pool[m][lane];
                int v = (int)(en & 1023);
                if (!((inc[v >> 5] >> (v & 31)) & 1u) && en < best) best = en;
            }
        }
        for (int off = 32; off; off >>= 1) {
            u64 o = __shfl_xor(best, off, 64);
            if (o < best) best = o;
        }
        if (best == ~0ull) break;                    // no frontier edge
        // ALL lanes know the winner: decode + issue next gather immediately
        uint32_t db = (uint32_t)(best >> 24);
        int e = (int)((best >> 10) & 0x3FFF);
        int v = (int)(best & 1023);
        float s = (__uint_as_float(db) - MN) / (MX - MN) + 0.5f;  // exact ref f32 ops
        int dvn = deg[v * DSTR];                     // broadcast load
        u64 gn = slots[(size_t)v * CAP + lane];      // independent gather
        if (lane == 0) {
            inc[v >> 5] |= 1u << (v & 31);
            members[nmem] = v;
            selU[i * 8 + cnt] = src[e];
            selV[i * 8 + cnt] = v;
            selS[i * 8 + cnt] = s;
        }
        pool[nmem][lane] = (lane < min(dvn, CAP)) ? gn : ~0ull;
        tot += s;                                    // f32, same order as reference
        nmem++; cnt++;
        __syncthreads();
    }
    __syncthreads();
    if (lane == 0) {
        selCnt[i] = cnt;
        u64 h = 1469598103934665603ull;
        for (int w = 0; w < 32; ++w) { h ^= inc[w]; h *= 1099511628211ull; }
        sig[i] = h;
        // pack dup candidates: members v<i (<=6), 10 bits each, count in low 4
        u64 d = 0; int nc = 0;
        for (int k = 1; k < nmem; ++k) {
            int v = members[k];
            if (v < i) { d |= ((u64)(uint32_t)v) << (4 + 10 * nc); ++nc; }
        }
        dc64[i] = d | (u64)nc;
    }
    if (lane < 32) masks[(size_t)i * 32 + lane] = inc[lane];
    // unfiltered maskT scatter: members are {i} ∪ selV
    if (lane < nmem) {
        int n = members[lane];
        atomicOr(&maskT[(size_t)n * 32 + (i >> 5)], 1u << (i & 31));
    }
}

// ---- K3: dedup-in-place + all four outputs, one block per row i ----
// keep[j] = no member v<j of cluster_j with sig[v]==sig[j]
__global__ void k_rows(const float* __restrict__ x, const int* __restrict__ deg,
                       const u64* __restrict__ slots,
                       const uint32_t* __restrict__ masks, const uint32_t* __restrict__ maskT,
                       const u64* __restrict__ sig, const u64* __restrict__ dc64,
                       const int* __restrict__ selU, const int* __restrict__ selV,
                       const float* __restrict__ selS, const int* __restrict__ selCnt,
                       float* __restrict__ outAdj, float* __restrict__ outAs,
                       float* __restrict__ outNsm, float* __restrict__ outX) {
    __shared__ u64 sigL[NN];
    __shared__ uint32_t keepb[32];
    __shared__ uint32_t R[32], MI[32], orow[32];
    __shared__ uint32_t part[8][32];
    __shared__ int list[512];
    __shared__ int s_lcnt;
    __shared__ int su[8], ssv[8];
    __shared__ float ss[8];
    __shared__ int s_c;
    int i = blockIdx.x, t = threadIdx.x;

    for (int j = t; j < NN; j += 256) sigL[j] = sig[j];
    if (t < 32) { keepb[t] = 0; R[t] = 0; MI[t] = masks[(size_t)i * 32 + t]; }
    if (t == 0) s_c = selCnt[i];
    if (t < 8) { su[t] = selU[i*8+t]; ssv[t] = selV[i*8+t]; ss[t] = selS[i*8+t]; }
    __syncthreads();

    // keep bits: 1 dc64 load per j (coalesced), sig compares from LDS
    for (int q = 0; q < 4; ++q) {
        int j = t + q * 256;
        u64 d = dc64[j];
        int cj = (int)(d & 15);
        u64 sj = sigL[j];
        bool dup = false;
        for (int k = 0; k < cj; ++k) {
            int v = (int)((d >> (4 + 10 * k)) & 1023);
            if (sigL[v] == sj) { dup = true; break; }
        }
        if (!dup) atomicOr(&keepb[j >> 5], 1u << (j & 31));
    }

    // R = nodes reachable by one edge from cluster i — flattened independent
    // gather; validity by deg (broadcast load per 64-slot group, independent)
    int c = s_c;
    int total = (c + 1) * CAP;                        // <= 448
    for (int k = t; k < total; k += 256) {
        int m = k >> 6;
        int u = (m == 0) ? i : ssv[m - 1];
        int dv = min(deg[u * DSTR], CAP);             // broadcast within group
        u64 en = slots[(size_t)u * CAP + (k & 63)];   // independent gather
        if ((k & 63) < dv) {
            int v = (int)(en & 1023);
            atomicOr(&R[v >> 5], 1u << (v & 31));
        }
    }
    __syncthreads();
    int kp = (keepb[i >> 5] >> (i & 31)) & 1;

    // expand R's set bits into a list — wave shuffle-scan prefix (no contended atomics)
    if (t < 64) {
        uint32_t bits = (t < 32) ? R[t] : 0u;
        int pc = __popc(bits);
        int inc_scan = pc;
        #pragma unroll
        for (int d = 1; d < 64; d <<= 1) {
            int o = __shfl_up(inc_scan, d, 64);
            if (t >= d) inc_scan += o;
        }
        int off = inc_scan - pc;                      // exclusive prefix
        if (t < 32) {
            while (bits) {
                int b = __ffs(bits) - 1;
                bits &= bits - 1;
                list[off++] = t * 32 + b;
            }
        }
        if (t == 31) s_lcnt = inc_scan;               // total count
    }
    __syncthreads();
    int lcnt = s_lcnt;

    // orow = OR over n in list of maskT[n]  (8 groups x 32 lanes, independent loads)
    int g = t >> 5, l = t & 31;
    uint32_t acc = 0;
    if (kp) {
        for (int k = g; k < lcnt; k += 8)
            acc |= maskT[(size_t)list[k] * 32 + l];   // coalesced over l
    }
    part[g][l] = acc;
    __syncthreads();
    if (t < 32) {
        uint32_t o = 0;
        for (int gg = 0; gg < 8; ++gg) o |= part[gg][t];
        orow[t] = o & keepb[t];                      // filter by keep[j]
    }
    __syncthreads();

    // ---- writes: thread t owns j0 = 4t..4t+3 (float4, fully coalesced) ----
    int j0 = t * 4;
    int w = j0 >> 5, sh = j0 & 31;
    float4 vadj = {0,0,0,0}, vas = {0,0,0,0}, vnsm = {0,0,0,0};
    if (kp) {
        uint32_t ob = orow[w] >> sh;
        uint32_t mb = MI[w] >> sh;
        vadj.x = ((ob     ) & 1) && (j0     != i) ? 1.0f : 0.0f;
        vadj.y = ((ob >> 1) & 1) && (j0 + 1 != i) ? 1.0f : 0.0f;
        vadj.z = ((ob >> 2) & 1) && (j0 + 2 != i) ? 1.0f : 0.0f;
        vadj.w = ((ob >> 3) & 1) && (j0 + 3 != i) ? 1.0f : 0.0f;
        vas.x = (mb      & 1) ? 1.0f : 0.0f;
        vas.y = ((mb>>1) & 1) ? 1.0f : 0.0f;
        vas.z = ((mb>>2) & 1) ? 1.0f : 0.0f;
        vas.w = ((mb>>3) & 1) ? 1.0f : 0.0f;
        for (int k = 0; k < c; ++k) {
            float h = ss[k] * 0.5f;
            int u = su[k], v = ssv[k];
            vnsm.x += ((u == j0    ) ? h : 0.0f) + ((v == j0    ) ? h : 0.0f);
            vnsm.y += ((u == j0 + 1) ? h : 0.0f) + ((v == j0 + 1) ? h : 0.0f);
            vnsm.z += ((u == j0 + 2) ? h : 0.0f) + ((v == j0 + 2) ? h : 0.0f);
            vnsm.w += ((u == j0 + 3) ? h : 0.0f) + ((v == j0 + 3) ? h : 0.0f);
        }
    }
    ((float4*)outAdj)[(size_t)i * (NN/4) + t] = vadj;
    ((float4*)outAs )[(size_t)i * (NN/4) + t] = vas;
    ((float4*)outNsm)[(size_t)i * (NN/4) + t] = vnsm;

    // ---- x_new row i: thread t = feature dim ----
    float accx = 0.0f;
    if (kp) {
        for (int k = 0; k < c; ++k) {
            float h = ss[k] * 0.5f;
            accx += h * x[(size_t)su[k] * DF + t];
            accx += h * x[(size_t)ssv[k] * DF + t];
        }
    }
    outX[(size_t)i * DF + t] = accx;
}

extern "C" void kernel_launch(void* const* d_in, const int* in_sizes, int n_in,
                              void* d_out, int out_size, void* d_ws, size_t ws_size,
                              hipStream_t stream) {
    const float* x = (const float*)d_in[0];
    const int* ei = (const int*)d_in[1];
    const int* src = ei;
    const int* dst = ei + NE;

    float* out = (float*)d_out;
    float* out_adj = out;                                  // N*N
    float* out_x   = out + (size_t)NN * NN;                // N*D
    float* out_as  = out_x + (size_t)NN * DF;              // N*N
    float* out_nsm = out_as + (size_t)NN * NN;             // N*N

    char* w = (char*)d_ws;
    u64*      slots = (u64*)w;       w += (size_t)NN * CAP * 8;   // no pre-fill needed
    u64*      sig   = (u64*)w;       w += (size_t)NN * 8;
    u64*      dc64  = (u64*)w;       w += (size_t)NN * 8;
    // ---- zeroed-by-k_zero region (contiguous, 192KB): deg(padded), maskT ----
    int*      deg   = (int*)w;       w += (size_t)NN * DSTR * 4;
    uint32_t* maskT = (uint32_t*)w;  w += (size_t)NN * 32 * 4;
    // ---- end zeroed region ----
    uint32_t* pmin  = (uint32_t*)w;  w += (size_t)NB2 * 4;
    uint32_t* pmax  = (uint32_t*)w;  w += (size_t)NB2 * 4;
    uint32_t* masks = (uint32_t*)w;  w += (size_t)NN * 32 * 4;
    int*      selU  = (int*)w;       w += (size_t)NN * 8 * 4;
    int*      selV  = (int*)w;       w += (size_t)NN * 8 * 4;
    float*    selS  = (float*)w;     w += (size_t)NN * 8 * 4;
    int*      selCnt= (int*)w;       w += (size_t)NN * 4;

    // (NN*DSTR + NN*32) * 4 B = 192 KB = 48 blocks * 256 threads * 16 B
    k_zero<<<48, 256, 0, stream>>>((uint4*)deg);
    k_dist_build<<<NB2, 256, 0, stream>>>(x, src, dst, deg, slots, pmin, pmax);
    k_search<<<NN, 64, 0, stream>>>(deg, slots, pmin, pmax, src,
                                    masks, maskT, selU, selV, selS, selCnt, sig, dc64);
    k_rows<<<NN, 256, 0, stream>>>(x, deg, slots, masks, maskT, sig, dc64,
                                   selU, selV, selS, selCnt,
                                   out_adj, out_as, out_nsm, out_x);
}